// Round 7
// baseline (165.073 us; speedup 1.0000x reference)
//
#include <hip/hip_runtime.h>
#include <hip/hip_bf16.h>

#define BB 32
#define CC 128
#define OO 128
#define HH 56
#define WW 56
#define KK 4
#define HW 3136
#define WPLANE 147456
#define EPSV 1e-5f

#define NPOS 348                  // 6 rows x 58 cols staged positions
#define UNITS 1392                // NPOS*4 16B-units per chunk
#define BUFB 22528                // bytes per LDS buffer (22272 data + 256 pad)

typedef __attribute__((ext_vector_type(8))) short short8v;
typedef __attribute__((ext_vector_type(4))) float f32x4;

static __device__ __forceinline__ void gload16(const void* g, void* l) {
    __builtin_amdgcn_global_load_lds((const __attribute__((address_space(1))) void*)g,
                                     (__attribute__((address_space(3))) void*)l, 16, 0, 0);
}

// ---- convert x -> bf16 channel-last [b][h][w][c], + per-(b,h,c) row sums ----
__global__ void convert_pool_kernel(const float* __restrict__ x,
                                    ushort* __restrict__ xbf,
                                    float* __restrict__ pooledp,
                                    ushort* __restrict__ zpage) {
    const int h = blockIdx.x, b = blockIdx.y;
    if (h == 0 && b == 0 && threadIdx.x < 32) zpage[threadIdx.x] = 0;
    __shared__ float xl[128 * 57];
    const float* xp = x + (size_t)(b * CC) * HW + h * WW;
    #pragma unroll
    for (int k = 0; k < 28; ++k) {
        int e = threadIdx.x + k * 256;          // 7168 elems
        int c = e / 56, w = e - c * 56;
        xl[c * 57 + w] = xp[(size_t)c * HW + w];
    }
    __syncthreads();
    ushort* op = xbf + ((size_t)(b * HH + h)) * WW * CC;
    #pragma unroll
    for (int k = 0; k < 7; ++k) {
        int f = threadIdx.x + k * 256;          // 1792 ushort4 units
        int w = f >> 5, c4 = (f & 31) * 4;
        ushort4 v;
        __hip_bfloat16 b0 = __float2bfloat16(xl[(c4 + 0) * 57 + w]);
        __hip_bfloat16 b1 = __float2bfloat16(xl[(c4 + 1) * 57 + w]);
        __hip_bfloat16 b2 = __float2bfloat16(xl[(c4 + 2) * 57 + w]);
        __hip_bfloat16 b3 = __float2bfloat16(xl[(c4 + 3) * 57 + w]);
        v.x = *(ushort*)&b0; v.y = *(ushort*)&b1;
        v.z = *(ushort*)&b2; v.w = *(ushort*)&b3;
        *(ushort4*)(op + (size_t)w * CC + c4) = v;
    }
    if (threadIdx.x < 128) {
        int c = threadIdx.x;
        float s = 0.f;
        #pragma unroll
        for (int w = 0; w < 56; ++w) s += xl[c * 57 + w];
        pooledp[((size_t)(b * HH + h)) * CC + c] = s;
    }
}

// ---- attention: reduce pooled partials + tiny MLP + softmax. block per b ----
__global__ void attn_kernel(const float* __restrict__ pooledp,
                            const float* __restrict__ fc1_w, const float* __restrict__ fc1_b,
                            const float* __restrict__ fc2_w, const float* __restrict__ fc2_b,
                            float* __restrict__ attn) {
    const int b = blockIdx.x, c = threadIdx.x;      // 128 threads
    float s = 0.f;
    for (int h = 0; h < HH; ++h) s += pooledp[((size_t)(b * HH + h)) * CC + c];
    const float pc = s * (1.0f / HW);
    __shared__ float red[8];
    const int lane = c & 63, wid = c >> 6;
    #pragma unroll
    for (int k = 0; k < KK; ++k) {
        float v = pc * fc1_w[k * CC + c];
        for (int off = 32; off > 0; off >>= 1) v += __shfl_down(v, off, 64);
        if (lane == 0) red[k * 2 + wid] = v;
    }
    __syncthreads();
    if (c == 0) {
        float hk[KK], z[KK], m = -1e30f, den = 0.f;
        #pragma unroll
        for (int k = 0; k < KK; ++k)
            hk[k] = fmaxf(red[k * 2] + red[k * 2 + 1] + fc1_b[k], 0.f);
        #pragma unroll
        for (int k = 0; k < KK; ++k) {
            float t = fc2_b[k];
            #pragma unroll
            for (int j = 0; j < KK; ++j) t += hk[j] * fc2_w[k * KK + j];
            z[k] = t; m = fmaxf(m, t);
        }
        #pragma unroll
        for (int k = 0; k < KK; ++k) { z[k] = expf(z[k] - m); den += z[k]; }
        #pragma unroll
        for (int k = 0; k < KK; ++k) attn[b * KK + k] = z[k] / den;
    }
}

// ---- agg_w[b][j][o][c] (bf16) + fused agg_b ----
__global__ void aggw_kernel(const float* __restrict__ attn, const float* __restrict__ weight,
                            const float* __restrict__ bias,
                            ushort* __restrict__ aggw, float* __restrict__ agg_b) {
    int idx = blockIdx.x * 256 + threadIdx.x;
    if (idx < BB * 9 * OO * CC) {
        int c = idx & 127;
        int t = idx >> 7;
        int o = t & 127;
        t >>= 7;
        int j = t % 9;
        int b = t / 9;
        size_t wi = ((size_t)(o * CC + c)) * 9 + j;
        float s = attn[b*KK + 0] * weight[wi]
                + attn[b*KK + 1] * weight[wi + (size_t)WPLANE]
                + attn[b*KK + 2] * weight[wi + (size_t)2*WPLANE]
                + attn[b*KK + 3] * weight[wi + (size_t)3*WPLANE];
        __hip_bfloat16 hb = __float2bfloat16(s);
        aggw[idx] = *(ushort*)&hb;
    }
    if (blockIdx.x < 16) {
        int i = blockIdx.x * 256 + threadIdx.x;   // 0..4095
        int b = i >> 7, o = i & 127;
        float s = 0.f;
        #pragma unroll
        for (int k = 0; k < KK; ++k) s += attn[b*KK + k] * bias[k*OO + o];
        agg_b[i] = s;
    }
}

// ---- implicit-GEMM conv: 448 blocks, 4 waves (2 o-half x 2 p-half),
//      gload_lds dbuf staging (src-permuted XOR swizzle), A reg-prefetch,
//      XCD swizzle, fused stats ----
__launch_bounds__(256, 3)
__global__ void conv_kernel(const ushort* __restrict__ xbf, const ushort* __restrict__ aggw,
                            const float* __restrict__ agg_b, const ushort* __restrict__ zpage,
                            float* __restrict__ out,
                            float* __restrict__ psum, float* __restrict__ psumsq) {
    // XCD-aware swizzle: each XCD gets 4 consecutive samples.
    const int lid  = blockIdx.x;
    const int gwid = (lid & 7) * 56 + (lid >> 3);
    const int b = gwid / 14;
    const int t = gwid - b * 14;
    const int h0 = t * 4;
    __shared__ ushort xs[2 * BUFB / 2];   // 45056 B

    const int tid  = threadIdx.x;
    const int lane = tid & 63;
    const int wid  = tid >> 6;
    const int wg = wid & 1;               // o base = wg*64
    const int wy = wid >> 1;              // p base = wy*112
    const int cf = lane & 15;
    const int kg = lane >> 4;

    // ---- staging setup: wave wid issues gload_lds for q = wid, wid+4, ... (<22)
    // LDS slot v (linear, lane*16) receives unit u = v ^ ((v>>3)&7) (involution,
    // source bits 3-5 disjoint from target bits 0-2). Invalid/halo -> zpage.
    const ushort* gp[6]; int gstep[6];
    #pragma unroll
    for (int k = 0; k < 6; ++k) {
        int q = wid + 4 * k;
        gp[k] = zpage; gstep[k] = 0;
        if (q < 22) {
            int v = q * 64 + lane;
            int u = v ^ ((v >> 3) & 7);
            int pos = u >> 2, quad = u & 3;
            int row = pos / 58, col = pos - row * 58;
            int gh = h0 - 1 + row, gw = col - 1;
            bool valid = (pos < NPOS) && (gh >= 0) && (gh < HH) && (gw >= 0) && (gw < WW);
            if (valid) {
                gp[k] = xbf + ((size_t)((b * HH + gh) * WW + gw)) * CC + quad * 8;
                gstep[k] = 32;
            }
        }
    }

    // B-frag linear byte offsets + output offsets
    int blin[7], oofs[7];
    #pragma unroll
    for (int nf = 0; nf < 7; ++nf) {
        int p = wy * 112 + nf * 16 + cf;
        int r = p / 56, w = p - r * 56;
        blin[nf] = (((r + 1) * 58 + (w + 1)) << 6) + kg * 16;
        oofs[nf] = (h0 + r) * WW + w;
    }

    f32x4 acc[4][7];
    #pragma unroll
    for (int mf = 0; mf < 4; ++mf)
        #pragma unroll
        for (int nf = 0; nf < 7; ++nf) acc[mf][nf] = (f32x4){0.f, 0.f, 0.f, 0.f};

    const ushort* Abase = aggw + (size_t)b * 9 * 16384 + (size_t)(wg * 64 + cf) * 128 + kg * 8;
    short8v pa[4];
    #pragma unroll
    for (int mf = 0; mf < 4; ++mf)
        pa[mf] = *(const short8v*)(Abase + mf * 2048);

    // prologue: stage chunk 0 into buf 0
    {
        char* base = (char*)xs;
        #pragma unroll
        for (int k = 0; k < 6; ++k) {
            int q = wid + 4 * k;
            if (q < 22) { gload16(gp[k], base + q * 1024); gp[k] += gstep[k]; }
        }
    }
    __syncthreads();

    int cur = 0;
    for (int ci = 0; ci < 4; ++ci) {
        const int c0 = ci * 32;
        if (ci < 3) {       // async-issue next chunk into the other buffer
            char* base = (char*)xs + (cur ^ 1) * BUFB;
            #pragma unroll
            for (int k = 0; k < 6; ++k) {
                int q = wid + 4 * k;
                if (q < 22) { gload16(gp[k], base + q * 1024); gp[k] += gstep[k]; }
            }
        }
        const int cbase = cur * BUFB;
        #pragma unroll
        for (int j = 0; j < 9; ++j) {
            const int toff = ((j/3 - 1) * 58 + (j%3 - 1)) * 64;
            short8v ca[4];
            #pragma unroll
            for (int mf = 0; mf < 4; ++mf) ca[mf] = pa[mf];
            // rolling A prefetch: next tap, or next chunk's tap 0
            if (j < 8) {
                #pragma unroll
                for (int mf = 0; mf < 4; ++mf)
                    pa[mf] = *(const short8v*)(Abase + (size_t)(j+1) * 16384 + mf * 2048 + c0);
            } else if (ci < 3) {
                #pragma unroll
                for (int mf = 0; mf < 4; ++mf)
                    pa[mf] = *(const short8v*)(Abase + mf * 2048 + c0 + 32);
            }
            #pragma unroll
            for (int nf = 0; nf < 7; ++nf) {
                int lin = cbase + blin[nf] + toff;
                int swz = lin ^ ((lin >> 3) & 0x70);
                short8v bf = *(const short8v*)((const char*)xs + swz);
                #pragma unroll
                for (int mf = 0; mf < 4; ++mf)
                    acc[mf][nf] = __builtin_amdgcn_mfma_f32_16x16x32_bf16(ca[mf], bf, acc[mf][nf], 0, 0, 0);
            }
        }
        if (ci < 3) __syncthreads();   // drains vmcnt (gloads landed) + LDS free
        cur ^= 1;
    }

    // epilogue: bias add, store, fused stats partials
    #pragma unroll
    for (int mf = 0; mf < 4; ++mf) {
        #pragma unroll
        for (int i = 0; i < 4; ++i) {
            const int o = wg * 64 + mf * 16 + kg * 4 + i;
            const float ab = agg_b[b * OO + o];
            float* op = out + ((size_t)(b * OO + o)) * HW;
            float s = 0.f, s2 = 0.f;
            #pragma unroll
            for (int nf = 0; nf < 7; ++nf) {
                float v = acc[mf][nf][i] + ab;
                op[oofs[nf]] = v;
                s += v; s2 += v * v;
            }
            s  += __shfl_xor(s, 1, 64);  s  += __shfl_xor(s, 2, 64);
            s  += __shfl_xor(s, 4, 64);  s  += __shfl_xor(s, 8, 64);
            s2 += __shfl_xor(s2, 1, 64); s2 += __shfl_xor(s2, 2, 64);
            s2 += __shfl_xor(s2, 4, 64); s2 += __shfl_xor(s2, 8, 64);
            if (cf == 0) {
                int row = (b * 14 + t) * 2 + wy;
                psum[row * OO + o]   = s;
                psumsq[row * OO + o] = s2;
            }
        }
    }
}

// ---- final stats: one block per channel ----
__global__ void finstats_kernel(const float* __restrict__ psum, const float* __restrict__ psumsq,
                                float* __restrict__ sums, float* __restrict__ sumsq) {
    const int o = blockIdx.x, l = threadIdx.x;   // 64 threads
    float s = 0.f, s2 = 0.f;
    for (int r = l; r < 896; r += 64) { s += psum[r * OO + o]; s2 += psumsq[r * OO + o]; }
    for (int off = 32; off > 0; off >>= 1) {
        s  += __shfl_down(s, off, 64);
        s2 += __shfl_down(s2, off, 64);
    }
    if (l == 0) { sums[o] = s; sumsq[o] = s2; }
}

// ---- BN + ReLU in place ----
__global__ void bn_kernel(float* __restrict__ out,
                          const float* __restrict__ sums, const float* __restrict__ sumsq,
                          const float* __restrict__ gamma, const float* __restrict__ beta) {
    const float invN = 1.0f / (float)(BB * HW);
    const int total4 = BB * OO * HW / 4;
    for (int i = blockIdx.x * blockDim.x + threadIdx.x; i < total4; i += gridDim.x * blockDim.x) {
        int o = (i / (HW/4)) % OO;
        float mean = sums[o] * invN;
        float var  = sumsq[o] * invN - mean*mean;
        float inv  = rsqrtf(var + EPSV);
        float g  = gamma[o] * inv;
        float bt = beta[o] - mean * g;
        float4 v = ((float4*)out)[i];
        v.x = fmaxf(v.x*g + bt, 0.f);
        v.y = fmaxf(v.y*g + bt, 0.f);
        v.z = fmaxf(v.z*g + bt, 0.f);
        v.w = fmaxf(v.w*g + bt, 0.f);
        ((float4*)out)[i] = v;
    }
}

extern "C" void kernel_launch(void* const* d_in, const int* in_sizes, int n_in,
                              void* d_out, int out_size, void* d_ws, size_t ws_size,
                              hipStream_t stream) {
    const float* x      = (const float*)d_in[0];
    const float* fc1_w  = (const float*)d_in[1];
    const float* fc1_b  = (const float*)d_in[2];
    const float* fc2_w  = (const float*)d_in[3];
    const float* fc2_b  = (const float*)d_in[4];
    const float* weight = (const float*)d_in[5];
    const float* bias   = (const float*)d_in[6];
    const float* gamma  = (const float*)d_in[7];
    const float* beta   = (const float*)d_in[8];
    float* out = (float*)d_out;

    const size_t XBF_ELEMS  = (size_t)BB * HW * CC;        // 12,845,056
    const size_t AGGW_ELEMS = (size_t)BB * 9 * OO * CC;    //  4,718,592
    ushort* xbf  = (ushort*)d_ws;
    ushort* aggw = xbf + XBF_ELEMS;
    float*  wsf  = (float*)(aggw + AGGW_ELEMS);
    float* pooledp = wsf;                    // 229376
    float* attn    = pooledp + 229376;       // 128
    float* agg_b   = attn + 128;             // 4096
    float* psum    = agg_b + 4096;           // 114688 (896*128)
    float* psumsq  = psum + 114688;          // 114688
    float* sums    = psumsq + 114688;        // 128
    float* sumsq   = sums + 128;             // 128
    ushort* zpage  = (ushort*)(sumsq + 128); // 32 shorts, zeroed by convert_pool

    convert_pool_kernel<<<dim3(HH, BB), 256, 0, stream>>>(x, xbf, pooledp, zpage);
    attn_kernel<<<BB, 128, 0, stream>>>(pooledp, fc1_w, fc1_b, fc2_w, fc2_b, attn);
    aggw_kernel<<<(int)((AGGW_ELEMS + 255)/256), 256, 0, stream>>>(attn, weight, bias, aggw, agg_b);
    conv_kernel<<<dim3(448), 256, 0, stream>>>(xbf, aggw, agg_b, zpage, out, psum, psumsq);
    finstats_kernel<<<OO, 64, 0, stream>>>(psum, psumsq, sums, sumsq);
    bn_kernel<<<2048, 256, 0, stream>>>(out, sums, sumsq, gamma, beta);
}

// Round 8
// 147.698 us; speedup vs baseline: 1.1176x; 1.1176x over previous
//
#include <hip/hip_runtime.h>
#include <hip/hip_bf16.h>

#define BB 32
#define CC 128
#define OO 128
#define HH 56
#define WW 56
#define KK 4
#define HW 3136
#define WPLANE 147456
#define EPSV 1e-5f

#define NPOS3 232                 // 4 rows x 58 cols staged positions
#define BUFB 15360                // bytes per LDS buffer (14848 data + pad to 1024-mult)

typedef __attribute__((ext_vector_type(8))) short short8v;
typedef __attribute__((ext_vector_type(4))) float f32x4;

static __device__ __forceinline__ void gload16(const void* g, void* l) {
    __builtin_amdgcn_global_load_lds((const __attribute__((address_space(1))) void*)g,
                                     (__attribute__((address_space(3))) void*)l, 16, 0, 0);
}

// ---- convert x -> bf16 channel-last [b][h][w][c], + per-(b,h,c) row sums ----
__global__ void convert_pool_kernel(const float* __restrict__ x,
                                    ushort* __restrict__ xbf,
                                    float* __restrict__ pooledp,
                                    ushort* __restrict__ zpage) {
    const int h = blockIdx.x, b = blockIdx.y;
    if (h == 0 && b == 0 && threadIdx.x < 32) zpage[threadIdx.x] = 0;
    __shared__ float xl[128 * 57];
    const float* xp = x + (size_t)(b * CC) * HW + h * WW;
    #pragma unroll
    for (int k = 0; k < 28; ++k) {
        int e = threadIdx.x + k * 256;          // 7168 elems
        int c = e / 56, w = e - c * 56;
        xl[c * 57 + w] = xp[(size_t)c * HW + w];
    }
    __syncthreads();
    ushort* op = xbf + ((size_t)(b * HH + h)) * WW * CC;
    #pragma unroll
    for (int k = 0; k < 7; ++k) {
        int f = threadIdx.x + k * 256;          // 1792 ushort4 units
        int w = f >> 5, c4 = (f & 31) * 4;
        ushort4 v;
        __hip_bfloat16 b0 = __float2bfloat16(xl[(c4 + 0) * 57 + w]);
        __hip_bfloat16 b1 = __float2bfloat16(xl[(c4 + 1) * 57 + w]);
        __hip_bfloat16 b2 = __float2bfloat16(xl[(c4 + 2) * 57 + w]);
        __hip_bfloat16 b3 = __float2bfloat16(xl[(c4 + 3) * 57 + w]);
        v.x = *(ushort*)&b0; v.y = *(ushort*)&b1;
        v.z = *(ushort*)&b2; v.w = *(ushort*)&b3;
        *(ushort4*)(op + (size_t)w * CC + c4) = v;
    }
    if (threadIdx.x < 128) {
        int c = threadIdx.x;
        float s = 0.f;
        #pragma unroll
        for (int w = 0; w < 56; ++w) s += xl[c * 57 + w];
        pooledp[((size_t)(b * HH + h)) * CC + c] = s;
    }
}

// ---- attention: reduce pooled partials + tiny MLP + softmax. block per b ----
__global__ void attn_kernel(const float* __restrict__ pooledp,
                            const float* __restrict__ fc1_w, const float* __restrict__ fc1_b,
                            const float* __restrict__ fc2_w, const float* __restrict__ fc2_b,
                            float* __restrict__ attn) {
    const int b = blockIdx.x, c = threadIdx.x;      // 128 threads
    float s = 0.f;
    for (int h = 0; h < HH; ++h) s += pooledp[((size_t)(b * HH + h)) * CC + c];
    const float pc = s * (1.0f / HW);
    __shared__ float red[8];
    const int lane = c & 63, wid = c >> 6;
    #pragma unroll
    for (int k = 0; k < KK; ++k) {
        float v = pc * fc1_w[k * CC + c];
        for (int off = 32; off > 0; off >>= 1) v += __shfl_down(v, off, 64);
        if (lane == 0) red[k * 2 + wid] = v;
    }
    __syncthreads();
    if (c == 0) {
        float hk[KK], z[KK], m = -1e30f, den = 0.f;
        #pragma unroll
        for (int k = 0; k < KK; ++k)
            hk[k] = fmaxf(red[k * 2] + red[k * 2 + 1] + fc1_b[k], 0.f);
        #pragma unroll
        for (int k = 0; k < KK; ++k) {
            float t = fc2_b[k];
            #pragma unroll
            for (int j = 0; j < KK; ++j) t += hk[j] * fc2_w[k * KK + j];
            z[k] = t; m = fmaxf(m, t);
        }
        #pragma unroll
        for (int k = 0; k < KK; ++k) { z[k] = expf(z[k] - m); den += z[k]; }
        #pragma unroll
        for (int k = 0; k < KK; ++k) attn[b * KK + k] = z[k] / den;
    }
}

// ---- agg_w[b][j][o][c] (bf16) + fused agg_b ----
__global__ void aggw_kernel(const float* __restrict__ attn, const float* __restrict__ weight,
                            const float* __restrict__ bias,
                            ushort* __restrict__ aggw, float* __restrict__ agg_b) {
    int idx = blockIdx.x * 256 + threadIdx.x;
    if (idx < BB * 9 * OO * CC) {
        int c = idx & 127;
        int t = idx >> 7;
        int o = t & 127;
        t >>= 7;
        int j = t % 9;
        int b = t / 9;
        size_t wi = ((size_t)(o * CC + c)) * 9 + j;
        float s = attn[b*KK + 0] * weight[wi]
                + attn[b*KK + 1] * weight[wi + (size_t)WPLANE]
                + attn[b*KK + 2] * weight[wi + (size_t)2*WPLANE]
                + attn[b*KK + 3] * weight[wi + (size_t)3*WPLANE];
        __hip_bfloat16 hb = __float2bfloat16(s);
        aggw[idx] = *(ushort*)&hb;
    }
    if (blockIdx.x < 16) {
        int i = blockIdx.x * 256 + threadIdx.x;   // 0..4095
        int b = i >> 7, o = i & 127;
        float s = 0.f;
        #pragma unroll
        for (int k = 0; k < KK; ++k) s += attn[b*KK + k] * bias[k*OO + o];
        agg_b[i] = s;
    }
}

// ---- implicit-GEMM conv: 896 blocks x 4 waves (4 o-groups of 32), wave=32o x 112p,
//      gload_lds dbuf staging (src-permuted XOR swizzle), A reg-prefetch,
//      XCD swizzle, fused stats ----
__launch_bounds__(256, 4)
__global__ void conv_kernel(const ushort* __restrict__ xbf, const ushort* __restrict__ aggw,
                            const float* __restrict__ agg_b, const ushort* __restrict__ zpage,
                            float* __restrict__ out,
                            float* __restrict__ psum, float* __restrict__ psumsq) {
    // XCD-aware swizzle: 896 blocks, each XCD gets 112 consecutive gwids = 4 samples.
    const int lid  = blockIdx.x;
    const int gwid = (lid & 7) * 112 + (lid >> 3);
    const int b = gwid / 28;
    const int t = gwid - b * 28;          // row-pair tile 0..27
    const int h0 = t * 2;
    __shared__ ushort xs[2 * BUFB / 2];   // 30720 B

    const int tid  = threadIdx.x;
    const int lane = tid & 63;
    const int wid  = tid >> 6;            // o-group: o base = wid*32
    const int cf = lane & 15;
    const int kg = lane >> 4;

    // ---- staging setup: unit un = tid + k*256 (k=0..3), LDS slot un*16 bytes.
    // Slot un receives global unit u = un ^ ((un>>3)&7) (involution, bits 3-5
    // XORed into bits 0-2, stays within 64-unit block). Halo/pad -> zpage.
    const ushort* gp[4]; int gstep[4];
    #pragma unroll
    for (int k = 0; k < 4; ++k) {
        int un = tid + k * 256;
        int u = un ^ ((un >> 3) & 7);
        int pos = u >> 2, quad = u & 3;
        int row = pos / 58, col = pos - row * 58;
        int gh = h0 - 1 + row, gw = col - 1;
        bool valid = (un < 960) && (pos < NPOS3) &&
                     (gh >= 0) && (gh < HH) && (gw >= 0) && (gw < WW);
        gp[k] = valid ? (xbf + ((size_t)((b * HH + gh) * WW + gw)) * CC + quad * 8) : zpage;
        gstep[k] = valid ? 32 : 0;
    }

    // B-frag intra-buffer byte offsets (linear, pre-swizzle)
    int blin[7];
    #pragma unroll
    for (int nf = 0; nf < 7; ++nf) {
        int p = nf * 16 + cf;
        int r = p / 56, w = p - r * 56;
        blin[nf] = (((r + 1) * 58 + (w + 1)) << 6) + kg * 16;
    }

    f32x4 acc[2][7];
    #pragma unroll
    for (int mf = 0; mf < 2; ++mf)
        #pragma unroll
        for (int nf = 0; nf < 7; ++nf) acc[mf][nf] = (f32x4){0.f, 0.f, 0.f, 0.f};

    const ushort* Abase = aggw + (size_t)b * 9 * 16384 + (size_t)(wid * 32 + cf) * 128 + kg * 8;
    short8v pa[2];
    #pragma unroll
    for (int mf = 0; mf < 2; ++mf)
        pa[mf] = *(const short8v*)(Abase + mf * 2048);

    // prologue: stage chunk 0 into buf 0 (LDS dest wave-uniform base + lane*16)
    #pragma unroll
    for (int k = 0; k < 4; ++k) {
        if (wid + k * 4 < 15) {
            gload16(gp[k], (char*)xs + (wid + k * 4) * 1024);
            gp[k] += gstep[k];
        }
    }
    __syncthreads();

    int cur = 0;
    for (int ci = 0; ci < 4; ++ci) {
        const int c0 = ci * 32;
        if (ci < 3) {       // async-issue next chunk into the other buffer
            char* base = (char*)xs + (cur ^ 1) * BUFB;
            #pragma unroll
            for (int k = 0; k < 4; ++k) {
                if (wid + k * 4 < 15) {
                    gload16(gp[k], base + (wid + k * 4) * 1024);
                    gp[k] += gstep[k];
                }
            }
        }
        const char* xbuf = (const char*)xs + cur * BUFB;
        #pragma unroll
        for (int j = 0; j < 9; ++j) {
            const int toff = ((j/3 - 1) * 58 + (j%3 - 1)) * 64;
            short8v ca[2];
            #pragma unroll
            for (int mf = 0; mf < 2; ++mf) ca[mf] = pa[mf];
            // rolling A prefetch: next tap, or next chunk's tap 0
            if (j < 8) {
                #pragma unroll
                for (int mf = 0; mf < 2; ++mf)
                    pa[mf] = *(const short8v*)(Abase + (size_t)(j+1) * 16384 + mf * 2048 + c0);
            } else if (ci < 3) {
                #pragma unroll
                for (int mf = 0; mf < 2; ++mf)
                    pa[mf] = *(const short8v*)(Abase + mf * 2048 + c0 + 32);
            }
            #pragma unroll
            for (int nf = 0; nf < 7; ++nf) {
                int lin = blin[nf] + toff;
                int swz = lin ^ ((lin >> 3) & 0x70);
                short8v bf = *(const short8v*)(xbuf + swz);
                #pragma unroll
                for (int mf = 0; mf < 2; ++mf)
                    acc[mf][nf] = __builtin_amdgcn_mfma_f32_16x16x32_bf16(ca[mf], bf, acc[mf][nf], 0, 0, 0);
            }
        }
        if (ci < 3) __syncthreads();
        cur ^= 1;
    }

    // ---- epilogue: bias add, store, fused stats partials ----
    #pragma unroll
    for (int mf = 0; mf < 2; ++mf) {
        #pragma unroll
        for (int i = 0; i < 4; ++i) {
            const int o = wid * 32 + mf * 16 + kg * 4 + i;
            const float ab = agg_b[b * OO + o];
            float* op = out + ((size_t)(b * OO + o)) * HW;
            float s = 0.f, s2 = 0.f;
            #pragma unroll
            for (int nf = 0; nf < 7; ++nf) {
                int p = nf * 16 + cf;
                int r = p / 56, w = p - r * 56;
                float v = acc[mf][nf][i] + ab;
                op[(h0 + r) * WW + w] = v;
                s += v; s2 += v * v;
            }
            s  += __shfl_xor(s, 1, 64);  s  += __shfl_xor(s, 2, 64);
            s  += __shfl_xor(s, 4, 64);  s  += __shfl_xor(s, 8, 64);
            s2 += __shfl_xor(s2, 1, 64); s2 += __shfl_xor(s2, 2, 64);
            s2 += __shfl_xor(s2, 4, 64); s2 += __shfl_xor(s2, 8, 64);
            if (cf == 0) {
                psum[gwid * OO + o]   = s;
                psumsq[gwid * OO + o] = s2;
            }
        }
    }
}

// ---- final stats: one block per channel ----
__global__ void finstats_kernel(const float* __restrict__ psum, const float* __restrict__ psumsq,
                                float* __restrict__ sums, float* __restrict__ sumsq) {
    const int o = blockIdx.x, l = threadIdx.x;   // 64 threads
    float s = 0.f, s2 = 0.f;
    for (int r = l; r < 896; r += 64) { s += psum[r * OO + o]; s2 += psumsq[r * OO + o]; }
    for (int off = 32; off > 0; off >>= 1) {
        s  += __shfl_down(s, off, 64);
        s2 += __shfl_down(s2, off, 64);
    }
    if (l == 0) { sums[o] = s; sumsq[o] = s2; }
}

// ---- BN + ReLU in place ----
__global__ void bn_kernel(float* __restrict__ out,
                          const float* __restrict__ sums, const float* __restrict__ sumsq,
                          const float* __restrict__ gamma, const float* __restrict__ beta) {
    const float invN = 1.0f / (float)(BB * HW);
    const int total4 = BB * OO * HW / 4;
    for (int i = blockIdx.x * blockDim.x + threadIdx.x; i < total4; i += gridDim.x * blockDim.x) {
        int o = (i / (HW/4)) % OO;
        float mean = sums[o] * invN;
        float var  = sumsq[o] * invN - mean*mean;
        float inv  = rsqrtf(var + EPSV);
        float g  = gamma[o] * inv;
        float bt = beta[o] - mean * g;
        float4 v = ((float4*)out)[i];
        v.x = fmaxf(v.x*g + bt, 0.f);
        v.y = fmaxf(v.y*g + bt, 0.f);
        v.z = fmaxf(v.z*g + bt, 0.f);
        v.w = fmaxf(v.w*g + bt, 0.f);
        ((float4*)out)[i] = v;
    }
}

extern "C" void kernel_launch(void* const* d_in, const int* in_sizes, int n_in,
                              void* d_out, int out_size, void* d_ws, size_t ws_size,
                              hipStream_t stream) {
    const float* x      = (const float*)d_in[0];
    const float* fc1_w  = (const float*)d_in[1];
    const float* fc1_b  = (const float*)d_in[2];
    const float* fc2_w  = (const float*)d_in[3];
    const float* fc2_b  = (const float*)d_in[4];
    const float* weight = (const float*)d_in[5];
    const float* bias   = (const float*)d_in[6];
    const float* gamma  = (const float*)d_in[7];
    const float* beta   = (const float*)d_in[8];
    float* out = (float*)d_out;

    const size_t XBF_ELEMS  = (size_t)BB * HW * CC;        // 12,845,056
    const size_t AGGW_ELEMS = (size_t)BB * 9 * OO * CC;    //  4,718,592
    ushort* xbf  = (ushort*)d_ws;
    ushort* aggw = xbf + XBF_ELEMS;
    float*  wsf  = (float*)(aggw + AGGW_ELEMS);
    float* pooledp = wsf;                    // 229376
    float* attn    = pooledp + 229376;       // 128
    float* agg_b   = attn + 128;             // 4096
    float* psum    = agg_b + 4096;           // 114688 (896*128)
    float* psumsq  = psum + 114688;          // 114688
    float* sums    = psumsq + 114688;        // 128
    float* sumsq   = sums + 128;             // 128
    ushort* zpage  = (ushort*)(sumsq + 128); // 32 shorts, zeroed by convert_pool

    convert_pool_kernel<<<dim3(HH, BB), 256, 0, stream>>>(x, xbf, pooledp, zpage);
    attn_kernel<<<BB, 128, 0, stream>>>(pooledp, fc1_w, fc1_b, fc2_w, fc2_b, attn);
    aggw_kernel<<<(int)((AGGW_ELEMS + 255)/256), 256, 0, stream>>>(attn, weight, bias, aggw, agg_b);
    conv_kernel<<<dim3(896), 256, 0, stream>>>(xbf, aggw, agg_b, zpage, out, psum, psumsq);
    finstats_kernel<<<OO, 64, 0, stream>>>(psum, psumsq, sums, sumsq);
    bn_kernel<<<2048, 256, 0, stream>>>(out, sums, sumsq, gamma, beta);
}

// Round 9
// 111.222 us; speedup vs baseline: 1.4842x; 1.3280x over previous
//
#include <hip/hip_runtime.h>
#include <hip/hip_bf16.h>

#define BB 32
#define CC 128
#define OO 128
#define HH 56
#define WW 56
#define KK 4
#define HW 3136
#define WPLANE 147456
#define EPSV 1e-5f

#define NPOS 348                  // 6 rows x 58 cols staged positions
#define BUFB 22528                // bytes per LDS buffer = 1408 units x 16B (incl pad)

typedef __attribute__((ext_vector_type(8))) short short8v;
typedef __attribute__((ext_vector_type(4))) float f32x4;

static __device__ __forceinline__ void gload16(const void* g, void* l) {
    __builtin_amdgcn_global_load_lds((const __attribute__((address_space(1))) void*)g,
                                     (__attribute__((address_space(3))) void*)l, 16, 0, 0);
}

// ---- convert x -> bf16 channel-last [b][h][w][c], + per-(b,h,c) row sums ----
__global__ void convert_pool_kernel(const float* __restrict__ x,
                                    ushort* __restrict__ xbf,
                                    float* __restrict__ pooledp,
                                    ushort* __restrict__ zpage) {
    const int h = blockIdx.x, b = blockIdx.y;
    if (h == 0 && b == 0 && threadIdx.x < 32) zpage[threadIdx.x] = 0;
    __shared__ float xl[128 * 57];
    const float* xp = x + (size_t)(b * CC) * HW + h * WW;
    #pragma unroll
    for (int k = 0; k < 28; ++k) {
        int e = threadIdx.x + k * 256;          // 7168 elems
        int c = e / 56, w = e - c * 56;
        xl[c * 57 + w] = xp[(size_t)c * HW + w];
    }
    __syncthreads();
    ushort* op = xbf + ((size_t)(b * HH + h)) * WW * CC;
    #pragma unroll
    for (int k = 0; k < 7; ++k) {
        int f = threadIdx.x + k * 256;          // 1792 ushort4 units
        int w = f >> 5, c4 = (f & 31) * 4;
        ushort4 v;
        __hip_bfloat16 b0 = __float2bfloat16(xl[(c4 + 0) * 57 + w]);
        __hip_bfloat16 b1 = __float2bfloat16(xl[(c4 + 1) * 57 + w]);
        __hip_bfloat16 b2 = __float2bfloat16(xl[(c4 + 2) * 57 + w]);
        __hip_bfloat16 b3 = __float2bfloat16(xl[(c4 + 3) * 57 + w]);
        v.x = *(ushort*)&b0; v.y = *(ushort*)&b1;
        v.z = *(ushort*)&b2; v.w = *(ushort*)&b3;
        *(ushort4*)(op + (size_t)w * CC + c4) = v;
    }
    if (threadIdx.x < 128) {
        int c = threadIdx.x;
        float s = 0.f;
        #pragma unroll
        for (int w = 0; w < 56; ++w) s += xl[c * 57 + w];
        pooledp[((size_t)(b * HH + h)) * CC + c] = s;
    }
}

// ---- attention: reduce pooled partials + tiny MLP + softmax. block per b ----
__global__ void attn_kernel(const float* __restrict__ pooledp,
                            const float* __restrict__ fc1_w, const float* __restrict__ fc1_b,
                            const float* __restrict__ fc2_w, const float* __restrict__ fc2_b,
                            float* __restrict__ attn) {
    const int b = blockIdx.x, c = threadIdx.x;      // 128 threads
    float s = 0.f;
    for (int h = 0; h < HH; ++h) s += pooledp[((size_t)(b * HH + h)) * CC + c];
    const float pc = s * (1.0f / HW);
    __shared__ float red[8];
    const int lane = c & 63, wid = c >> 6;
    #pragma unroll
    for (int k = 0; k < KK; ++k) {
        float v = pc * fc1_w[k * CC + c];
        for (int off = 32; off > 0; off >>= 1) v += __shfl_down(v, off, 64);
        if (lane == 0) red[k * 2 + wid] = v;
    }
    __syncthreads();
    if (c == 0) {
        float hk[KK], z[KK], m = -1e30f, den = 0.f;
        #pragma unroll
        for (int k = 0; k < KK; ++k)
            hk[k] = fmaxf(red[k * 2] + red[k * 2 + 1] + fc1_b[k], 0.f);
        #pragma unroll
        for (int k = 0; k < KK; ++k) {
            float t = fc2_b[k];
            #pragma unroll
            for (int j = 0; j < KK; ++j) t += hk[j] * fc2_w[k * KK + j];
            z[k] = t; m = fmaxf(m, t);
        }
        #pragma unroll
        for (int k = 0; k < KK; ++k) { z[k] = expf(z[k] - m); den += z[k]; }
        #pragma unroll
        for (int k = 0; k < KK; ++k) attn[b * KK + k] = z[k] / den;
    }
}

// ---- agg_w (bf16) in layout [b][j][ci][o][c32] + fused agg_b ----
// element (b,j,ci,o,cc) = sum_k attn[b,k] * weight[k][o][ci*32+cc][j]
__global__ void aggw_kernel(const float* __restrict__ attn, const float* __restrict__ weight,
                            const float* __restrict__ bias,
                            ushort* __restrict__ aggw, float* __restrict__ agg_b) {
    int idx = blockIdx.x * 256 + threadIdx.x;
    if (idx < BB * 9 * OO * CC) {
        int cc = idx & 31;
        int t1 = idx >> 5;
        int o  = t1 & 127;
        int t2 = t1 >> 7;
        int ci = t2 & 3;
        int t3 = t2 >> 2;
        int j  = t3 % 9;
        int b  = t3 / 9;
        int c  = ci * 32 + cc;
        size_t wi = ((size_t)(o * CC + c)) * 9 + j;
        float s = attn[b*KK + 0] * weight[wi]
                + attn[b*KK + 1] * weight[wi + (size_t)WPLANE]
                + attn[b*KK + 2] * weight[wi + (size_t)2*WPLANE]
                + attn[b*KK + 3] * weight[wi + (size_t)3*WPLANE];
        __hip_bfloat16 hb = __float2bfloat16(s);
        aggw[idx] = *(ushort*)&hb;
    }
    if (blockIdx.x < 16) {
        int i = blockIdx.x * 256 + threadIdx.x;   // 0..4095
        int b = i >> 7, o = i & 127;
        float s = 0.f;
        #pragma unroll
        for (int k = 0; k < KK; ++k) s += attn[b*KK + k] * bias[k*OO + o];
        agg_b[i] = s;
    }
}

// ---- implicit-GEMM conv: 448 blocks x 4 waves (2 o-half x 2 p-half), M_wave=64,
//      gload_lds dbuf staging (src-permuted XOR swizzle), B-read software pipeline,
//      A rolling prefetch (coalesced layout), XCD swizzle, fused stats ----
__launch_bounds__(256, 2)
__global__ void conv_kernel(const ushort* __restrict__ xbf, const ushort* __restrict__ aggw,
                            const float* __restrict__ agg_b, const ushort* __restrict__ zpage,
                            float* __restrict__ out,
                            float* __restrict__ psum, float* __restrict__ psumsq) {
    // XCD-aware swizzle: each XCD gets 4 consecutive samples.
    const int lid  = blockIdx.x;
    const int gwid = (lid & 7) * 56 + (lid >> 3);
    const int b = gwid / 14;
    const int t = gwid - b * 14;
    const int h0 = t * 4;
    __shared__ ushort xs[2 * BUFB / 2];   // 45056 B

    const int tid  = threadIdx.x;
    const int lane = tid & 63;
    const int wid  = tid >> 6;
    const int wg = wid & 1;               // o base = wg*64
    const int wy = wid >> 1;              // p base = wy*112
    const int cf = lane & 15;
    const int kg = lane >> 4;

    // ---- staging: 1392 data units (+16 pad). q-block = 64 units; wave wid
    // handles q = wid, wid+4, ..., wid+20 (q<22). LDS slot un = q*64+lane
    // receives global unit u = un ^ ((un>>3)&7)  (involution, bits 3-5 -> 0-2).
    const ushort* gp[6]; int gstep[6];
    #pragma unroll
    for (int k = 0; k < 6; ++k) {
        int q = wid + 4 * k;
        int un = q * 64 + lane;
        int u = un ^ ((un >> 3) & 7);
        int pos = u >> 2, quad = u & 3;
        int row = pos / 58, col = pos - row * 58;
        int gh = h0 - 1 + row, gw = col - 1;
        bool valid = (pos < NPOS) && (gh >= 0) && (gh < HH) && (gw >= 0) && (gw < WW);
        gp[k] = valid ? (xbf + ((size_t)((b * HH + gh) * WW + gw)) * CC + quad * 8) : zpage;
        gstep[k] = valid ? 32 : 0;
    }

    // B-frag intra-buffer byte offsets (linear, pre-swizzle)
    int blin[7];
    #pragma unroll
    for (int nf = 0; nf < 7; ++nf) {
        int p = wy * 112 + nf * 16 + cf;
        int r = p / 56, w = p - r * 56;
        blin[nf] = (((r + 1) * 58 + (w + 1)) << 6) + kg * 16;
    }

    f32x4 acc[4][7];
    #pragma unroll
    for (int mf = 0; mf < 4; ++mf)
        #pragma unroll
        for (int nf = 0; nf < 7; ++nf) acc[mf][nf] = (f32x4){0.f, 0.f, 0.f, 0.f};

    // A: aggw [b][j][ci][o][c32]; lane (cf,kg) of frag mf reads o=wg*64+mf*16+cf,
    // 8 ch at kg*8 -> one fully-coalesced 1KB load per (mf) wave-instruction.
    const ushort* Ab = aggw + ((size_t)b * 36) * 4096 + (size_t)(wg * 64 + cf) * 32 + kg * 8;
    #define ALOAD(mf_, j_, ci_) (*(const short8v*)(Ab + (size_t)((j_) * 4 + (ci_)) * 4096 + (mf_) * 512))

    short8v pa[4];
    #pragma unroll
    for (int mf = 0; mf < 4; ++mf) pa[mf] = ALOAD(mf, 0, 0);

    // prologue: stage chunk 0 into buf 0
    #pragma unroll
    for (int k = 0; k < 6; ++k) {
        int q = wid + 4 * k;
        if (q < 22) { gload16(gp[k], (char*)xs + q * 1024); gp[k] += gstep[k]; }
    }
    __syncthreads();

    int cur = 0;
    for (int ci = 0; ci < 4; ++ci) {
        if (ci < 3) {       // async-issue next chunk into the other buffer
            char* base = (char*)xs + (cur ^ 1) * BUFB;
            #pragma unroll
            for (int k = 0; k < 6; ++k) {
                int q = wid + 4 * k;
                if (q < 22) { gload16(gp[k], base + q * 1024); gp[k] += gstep[k]; }
            }
        }
        const char* xbuf = (const char*)xs + cur * BUFB;

        // software-pipelined taps: read tap j+1 while MFMA-ing tap j
        short8v bfc[7], bfn[7];
        #pragma unroll
        for (int nf = 0; nf < 7; ++nf) {
            int lin = blin[nf] + (-58 - 1) * 64;        // tap 0 (dh=-1,dw=-1)
            int swz = lin ^ ((lin >> 3) & 0x70);
            bfc[nf] = *(const short8v*)(xbuf + swz);
        }
        #pragma unroll
        for (int j = 0; j < 9; ++j) {
            if (j < 8) {
                const int toff = (((j+1)/3 - 1) * 58 + ((j+1)%3 - 1)) * 64;
                #pragma unroll
                for (int nf = 0; nf < 7; ++nf) {
                    int lin = blin[nf] + toff;
                    int swz = lin ^ ((lin >> 3) & 0x70);
                    bfn[nf] = *(const short8v*)(xbuf + swz);
                }
            }
            short8v ca[4];
            #pragma unroll
            for (int mf = 0; mf < 4; ++mf) ca[mf] = pa[mf];
            if (j < 8) {
                #pragma unroll
                for (int mf = 0; mf < 4; ++mf) pa[mf] = ALOAD(mf, j + 1, ci);
            } else if (ci < 3) {
                #pragma unroll
                for (int mf = 0; mf < 4; ++mf) pa[mf] = ALOAD(mf, 0, ci + 1);
            }
            #pragma unroll
            for (int nf = 0; nf < 7; ++nf) {
                #pragma unroll
                for (int mf = 0; mf < 4; ++mf)
                    acc[mf][nf] = __builtin_amdgcn_mfma_f32_16x16x32_bf16(ca[mf], bfc[nf], acc[mf][nf], 0, 0, 0);
            }
            if (j < 8) {
                #pragma unroll
                for (int nf = 0; nf < 7; ++nf) bfc[nf] = bfn[nf];
            }
        }
        if (ci < 3) __syncthreads();
        cur ^= 1;
    }

    // ---- epilogue: bias add, store, fused stats partials ----
    #pragma unroll
    for (int mf = 0; mf < 4; ++mf) {
        #pragma unroll
        for (int i = 0; i < 4; ++i) {
            const int o = wg * 64 + mf * 16 + kg * 4 + i;
            const float ab = agg_b[b * OO + o];
            float* op = out + ((size_t)(b * OO + o)) * HW;
            float s = 0.f, s2 = 0.f;
            #pragma unroll
            for (int nf = 0; nf < 7; ++nf) {
                int p = wy * 112 + nf * 16 + cf;
                int r = p / 56, w = p - r * 56;
                float v = acc[mf][nf][i] + ab;
                op[(h0 + r) * WW + w] = v;
                s += v; s2 += v * v;
            }
            s  += __shfl_xor(s, 1, 64);  s  += __shfl_xor(s, 2, 64);
            s  += __shfl_xor(s, 4, 64);  s  += __shfl_xor(s, 8, 64);
            s2 += __shfl_xor(s2, 1, 64); s2 += __shfl_xor(s2, 2, 64);
            s2 += __shfl_xor(s2, 4, 64); s2 += __shfl_xor(s2, 8, 64);
            if (cf == 0) {
                int row = (b * 14 + t) * 2 + wy;
                psum[row * OO + o]   = s;
                psumsq[row * OO + o] = s2;
            }
        }
    }
}

// ---- final stats: one block per channel ----
__global__ void finstats_kernel(const float* __restrict__ psum, const float* __restrict__ psumsq,
                                float* __restrict__ sums, float* __restrict__ sumsq) {
    const int o = blockIdx.x, l = threadIdx.x;   // 64 threads
    float s = 0.f, s2 = 0.f;
    for (int r = l; r < 896; r += 64) { s += psum[r * OO + o]; s2 += psumsq[r * OO + o]; }
    for (int off = 32; off > 0; off >>= 1) {
        s  += __shfl_down(s, off, 64);
        s2 += __shfl_down(s2, off, 64);
    }
    if (l == 0) { sums[o] = s; sumsq[o] = s2; }
}

// ---- BN + ReLU in place ----
__global__ void bn_kernel(float* __restrict__ out,
                          const float* __restrict__ sums, const float* __restrict__ sumsq,
                          const float* __restrict__ gamma, const float* __restrict__ beta) {
    const float invN = 1.0f / (float)(BB * HW);
    const int total4 = BB * OO * HW / 4;
    for (int i = blockIdx.x * blockDim.x + threadIdx.x; i < total4; i += gridDim.x * blockDim.x) {
        int o = (i / (HW/4)) % OO;
        float mean = sums[o] * invN;
        float var  = sumsq[o] * invN - mean*mean;
        float inv  = rsqrtf(var + EPSV);
        float g  = gamma[o] * inv;
        float bt = beta[o] - mean * g;
        float4 v = ((float4*)out)[i];
        v.x = fmaxf(v.x*g + bt, 0.f);
        v.y = fmaxf(v.y*g + bt, 0.f);
        v.z = fmaxf(v.z*g + bt, 0.f);
        v.w = fmaxf(v.w*g + bt, 0.f);
        ((float4*)out)[i] = v;
    }
}

extern "C" void kernel_launch(void* const* d_in, const int* in_sizes, int n_in,
                              void* d_out, int out_size, void* d_ws, size_t ws_size,
                              hipStream_t stream) {
    const float* x      = (const float*)d_in[0];
    const float* fc1_w  = (const float*)d_in[1];
    const float* fc1_b  = (const float*)d_in[2];
    const float* fc2_w  = (const float*)d_in[3];
    const float* fc2_b  = (const float*)d_in[4];
    const float* weight = (const float*)d_in[5];
    const float* bias   = (const float*)d_in[6];
    const float* gamma  = (const float*)d_in[7];
    const float* beta   = (const float*)d_in[8];
    float* out = (float*)d_out;

    const size_t XBF_ELEMS  = (size_t)BB * HW * CC;        // 12,845,056
    const size_t AGGW_ELEMS = (size_t)BB * 9 * OO * CC;    //  4,718,592
    ushort* xbf  = (ushort*)d_ws;
    ushort* aggw = xbf + XBF_ELEMS;
    float*  wsf  = (float*)(aggw + AGGW_ELEMS);
    float* pooledp = wsf;                    // 229376
    float* attn    = pooledp + 229376;       // 128
    float* agg_b   = attn + 128;             // 4096
    float* psum    = agg_b + 4096;           // 114688 (896*128)
    float* psumsq  = psum + 114688;          // 114688
    float* sums    = psumsq + 114688;        // 128
    float* sumsq   = sums + 128;             // 128
    ushort* zpage  = (ushort*)(sumsq + 128); // 32 shorts, zeroed by convert_pool

    convert_pool_kernel<<<dim3(HH, BB), 256, 0, stream>>>(x, xbf, pooledp, zpage);
    attn_kernel<<<BB, 128, 0, stream>>>(pooledp, fc1_w, fc1_b, fc2_w, fc2_b, attn);
    aggw_kernel<<<(int)((AGGW_ELEMS + 255)/256), 256, 0, stream>>>(attn, weight, bias, aggw, agg_b);
    conv_kernel<<<dim3(448), 256, 0, stream>>>(xbf, aggw, agg_b, zpage, out, psum, psumsq);
    finstats_kernel<<<OO, 64, 0, stream>>>(psum, psumsq, sums, sumsq);
    bn_kernel<<<2048, 256, 0, stream>>>(out, sums, sumsq, gamma, beta);
}

// Round 10
// 110.805 us; speedup vs baseline: 1.4898x; 1.0038x over previous
//
#include <hip/hip_runtime.h>
#include <hip/hip_bf16.h>

#define BB 32
#define CC 128
#define OO 128
#define HH 56
#define WW 56
#define KK 4
#define HW 3136
#define WPLANE 147456
#define EPSV 1e-5f

#define NP4 232                   // 4 input rows x 58 cols staged positions
#define BUF4 15360                // bytes per LDS buffer: 960 units x 16 B (928 data + pad)

typedef __attribute__((ext_vector_type(8))) short short8v;
typedef __attribute__((ext_vector_type(4))) float f32x4;

static __device__ __forceinline__ void gload16(const void* g, void* l) {
    __builtin_amdgcn_global_load_lds((const __attribute__((address_space(1))) void*)g,
                                     (__attribute__((address_space(3))) void*)l, 16, 0, 0);
}

// ---- convert x -> bf16 channel-last [b][h][w][c], + per-(b,h,c) row sums ----
// float4 loads, XOR-swizzled LDS (conflict-free), ushort8 coalesced stores.
__global__ void convert_pool_kernel(const float* __restrict__ x,
                                    ushort* __restrict__ xbf,
                                    float* __restrict__ pooledp,
                                    ushort* __restrict__ zpage) {
    const int h = blockIdx.x, b = blockIdx.y;
    if (h == 0 && b == 0 && threadIdx.x < 32) zpage[threadIdx.x] = 0;
    __shared__ float4 xl4[1792];               // [c][w4] swizzled, 28672 B
    const float* xp = x + (size_t)(b * CC) * HW + h * WW;

    // load: 1792 float4 units, u -> (c = u/14, w4 = u%14); swizzle su = u ^ ((c>>3)&7)
    #pragma unroll
    for (int k = 0; k < 7; ++k) {
        int u = threadIdx.x + k * 256;
        int c = u / 14, w4 = u - c * 14;
        float4 v = *(const float4*)(xp + (size_t)c * HW + w4 * 4);
        xl4[u ^ ((c >> 3) & 7)] = v;
    }
    __syncthreads();

    // transpose+convert: 896 ushort8 units, v -> (w = v>>4, c8 = v&15)
    const float* xf = (const float*)xl4;
    #pragma unroll
    for (int k = 0; k < 4; ++k) {
        int v = threadIdx.x + k * 256;
        if (v < 896) {
            int w = v >> 4, c8 = v & 15;
            int w4 = w >> 2, wo = w & 3;
            short8v res;
            #pragma unroll
            for (int j = 0; j < 8; ++j) {
                int c = c8 * 8 + j;
                int su = (c * 14 + w4) ^ (c8 & 7);   // (c>>3) == c8 for j<8
                __hip_bfloat16 hb = __float2bfloat16(xf[su * 4 + wo]);
                res[j] = *(short*)&hb;
            }
            *(short8v*)(xbf + ((size_t)((b * HH + h) * WW + w)) * CC + c8 * 8) = res;
        }
    }

    // pooling partials
    if (threadIdx.x < 128) {
        int c = threadIdx.x;
        float s = 0.f;
        #pragma unroll
        for (int w4 = 0; w4 < 14; ++w4) {
            float4 v = xl4[(c * 14 + w4) ^ ((c >> 3) & 7)];
            s += v.x + v.y + v.z + v.w;
        }
        pooledp[((size_t)(b * HH + h)) * CC + c] = s;
    }
}

// ---- attention: reduce pooled partials + tiny MLP + softmax. block per b ----
__global__ void attn_kernel(const float* __restrict__ pooledp,
                            const float* __restrict__ fc1_w, const float* __restrict__ fc1_b,
                            const float* __restrict__ fc2_w, const float* __restrict__ fc2_b,
                            float* __restrict__ attn) {
    const int b = blockIdx.x, c = threadIdx.x;      // 128 threads
    float s = 0.f;
    for (int h = 0; h < HH; ++h) s += pooledp[((size_t)(b * HH + h)) * CC + c];
    const float pc = s * (1.0f / HW);
    __shared__ float red[8];
    const int lane = c & 63, wid = c >> 6;
    #pragma unroll
    for (int k = 0; k < KK; ++k) {
        float v = pc * fc1_w[k * CC + c];
        for (int off = 32; off > 0; off >>= 1) v += __shfl_down(v, off, 64);
        if (lane == 0) red[k * 2 + wid] = v;
    }
    __syncthreads();
    if (c == 0) {
        float hk[KK], z[KK], m = -1e30f, den = 0.f;
        #pragma unroll
        for (int k = 0; k < KK; ++k)
            hk[k] = fmaxf(red[k * 2] + red[k * 2 + 1] + fc1_b[k], 0.f);
        #pragma unroll
        for (int k = 0; k < KK; ++k) {
            float t = fc2_b[k];
            #pragma unroll
            for (int j = 0; j < KK; ++j) t += hk[j] * fc2_w[k * KK + j];
            z[k] = t; m = fmaxf(m, t);
        }
        #pragma unroll
        for (int k = 0; k < KK; ++k) { z[k] = expf(z[k] - m); den += z[k]; }
        #pragma unroll
        for (int k = 0; k < KK; ++k) attn[b * KK + k] = z[k] / den;
    }
}

// ---- agg_w (bf16) in layout [b][j][ci][o][c32] + fused agg_b ----
__global__ void aggw_kernel(const float* __restrict__ attn, const float* __restrict__ weight,
                            const float* __restrict__ bias,
                            ushort* __restrict__ aggw, float* __restrict__ agg_b) {
    int idx = blockIdx.x * 256 + threadIdx.x;
    if (idx < BB * 9 * OO * CC) {
        int cc = idx & 31;
        int t1 = idx >> 5;
        int o  = t1 & 127;
        int t2 = t1 >> 7;
        int ci = t2 & 3;
        int t3 = t2 >> 2;
        int j  = t3 % 9;
        int b  = t3 / 9;
        int c  = ci * 32 + cc;
        size_t wi = ((size_t)(o * CC + c)) * 9 + j;
        float s = attn[b*KK + 0] * weight[wi]
                + attn[b*KK + 1] * weight[wi + (size_t)WPLANE]
                + attn[b*KK + 2] * weight[wi + (size_t)2*WPLANE]
                + attn[b*KK + 3] * weight[wi + (size_t)3*WPLANE];
        __hip_bfloat16 hb = __float2bfloat16(s);
        aggw[idx] = *(ushort*)&hb;
    }
    if (blockIdx.x < 16) {
        int i = blockIdx.x * 256 + threadIdx.x;   // 0..4095
        int b = i >> 7, o = i & 127;
        float s = 0.f;
        #pragma unroll
        for (int k = 0; k < KK; ++k) s += attn[b*KK + k] * bias[k*OO + o];
        agg_b[i] = s;
    }
}

// ---- implicit-GEMM conv: 896 blocks x 4 waves (4 o-quarters x full 112p),
//      M_wave=32, 2-row tiles, gload_lds dbuf (src-permuted XOR swizzle),
//      A rolling prefetch (staging issued AFTER tap loop to keep vmcnt clean),
//      XCD swizzle, fused stats ----
__launch_bounds__(256, 2)
__global__ void conv_kernel(const ushort* __restrict__ xbf, const ushort* __restrict__ aggw,
                            const float* __restrict__ agg_b, const ushort* __restrict__ zpage,
                            float* __restrict__ out,
                            float* __restrict__ psum, float* __restrict__ psumsq) {
    // XCD-aware swizzle: 896 blocks, each XCD gets 112 consecutive gwids = 4 samples.
    const int lid  = blockIdx.x;
    const int gwid = (lid & 7) * 112 + (lid >> 3);
    const int b = gwid / 28;
    const int t = gwid - b * 28;          // row-pair tile 0..27
    const int h0 = t * 2;
    __shared__ ushort xs[2 * BUF4 / 2];   // 30720 B

    const int tid  = threadIdx.x;
    const int lane = tid & 63;
    const int wid  = tid >> 6;            // o-quarter: o base = wid*32
    const int cf = lane & 15;
    const int kg = lane >> 4;

    // staging: 928 data units (960 incl pad), q-blocks of 64; wave wid handles
    // q = wid+4k (k<4, q<15). LDS slot un = q*64+lane receives global unit
    // u = un ^ ((un>>3)&7) (involution within aligned 8-blocks). Halo/pad -> zpage.
    const ushort* gp[4]; int gstep[4];
    #pragma unroll
    for (int k = 0; k < 4; ++k) {
        int q = wid + 4 * k;
        int un = q * 64 + lane;
        int u = un ^ ((un >> 3) & 7);
        int pos = u >> 2, quad = u & 3;
        int row = pos / 58, col = pos - row * 58;
        int gh = h0 - 1 + row, gw = col - 1;
        bool valid = (pos < NP4) && (gh >= 0) && (gh < HH) && (gw >= 0) && (gw < WW);
        gp[k] = valid ? (xbf + ((size_t)((b * HH + gh) * WW + gw)) * CC + quad * 8) : zpage;
        gstep[k] = valid ? 32 : 0;
    }

    // B-frag intra-buffer byte offsets (linear, pre-swizzle)
    int blin[7];
    #pragma unroll
    for (int nf = 0; nf < 7; ++nf) {
        int p = nf * 16 + cf;
        int r = p / 56, w = p - r * 56;
        blin[nf] = (((r + 1) * 58 + (w + 1)) << 6) + kg * 16;
    }

    f32x4 acc[2][7];
    #pragma unroll
    for (int mf = 0; mf < 2; ++mf)
        #pragma unroll
        for (int nf = 0; nf < 7; ++nf) acc[mf][nf] = (f32x4){0.f, 0.f, 0.f, 0.f};

    // A: aggw [b][j][ci][o][c32]; coalesced 1KB wave loads
    const ushort* Ab = aggw + ((size_t)b * 36) * 4096 + (size_t)(wid * 32 + cf) * 32 + kg * 8;
    #define ALOAD(mf_, j_, ci_) (*(const short8v*)(Ab + (size_t)((j_) * 4 + (ci_)) * 4096 + (mf_) * 512))

    short8v pa[2];
    pa[0] = ALOAD(0, 0, 0);
    pa[1] = ALOAD(1, 0, 0);

    // prologue: stage chunk 0 into buf 0
    #pragma unroll
    for (int k = 0; k < 4; ++k) {
        int q = wid + 4 * k;
        if (q < 15) { gload16(gp[k], (char*)xs + q * 1024); gp[k] += gstep[k]; }
    }
    __syncthreads();

    int cur = 0;
    for (int ci = 0; ci < 4; ++ci) {
        const char* xbuf = (const char*)xs + cur * BUF4;
        #pragma unroll
        for (int j = 0; j < 9; ++j) {
            const int toff = ((j/3 - 1) * 58 + (j%3 - 1)) * 64;
            short8v ca0 = pa[0], ca1 = pa[1];
            if (j < 8) {
                pa[0] = ALOAD(0, j + 1, ci);
                pa[1] = ALOAD(1, j + 1, ci);
            } else if (ci < 3) {
                pa[0] = ALOAD(0, 0, ci + 1);
                pa[1] = ALOAD(1, 0, ci + 1);
            }
            #pragma unroll
            for (int nf = 0; nf < 7; ++nf) {
                int lin = blin[nf] + toff;
                int swz = lin ^ ((lin >> 3) & 0x70);
                short8v bf = *(const short8v*)(xbuf + swz);
                acc[0][nf] = __builtin_amdgcn_mfma_f32_16x16x32_bf16(ca0, bf, acc[0][nf], 0, 0, 0);
                acc[1][nf] = __builtin_amdgcn_mfma_f32_16x16x32_bf16(ca1, bf, acc[1][nf], 0, 0, 0);
            }
        }
        if (ci < 3) {
            // staging issued AFTER all A-loads of this chunk: pa vmcnt waits never
            // drain the staging queue; barrier drain covers completion.
            char* base = (char*)xs + (cur ^ 1) * BUF4;
            #pragma unroll
            for (int k = 0; k < 4; ++k) {
                int q = wid + 4 * k;
                if (q < 15) { gload16(gp[k], base + q * 1024); gp[k] += gstep[k]; }
            }
            __syncthreads();
            cur ^= 1;
        }
    }

    // ---- epilogue: bias add, store, fused stats partials ----
    #pragma unroll
    for (int mf = 0; mf < 2; ++mf) {
        #pragma unroll
        for (int i = 0; i < 4; ++i) {
            const int o = wid * 32 + mf * 16 + kg * 4 + i;
            const float ab = agg_b[b * OO + o];
            float* op = out + ((size_t)(b * OO + o)) * HW;
            float s = 0.f, s2 = 0.f;
            #pragma unroll
            for (int nf = 0; nf < 7; ++nf) {
                int p = nf * 16 + cf;
                int r = p / 56, w = p - r * 56;
                float v = acc[mf][nf][i] + ab;
                op[(h0 + r) * WW + w] = v;
                s += v; s2 += v * v;
            }
            s  += __shfl_xor(s, 1, 64);  s  += __shfl_xor(s, 2, 64);
            s  += __shfl_xor(s, 4, 64);  s  += __shfl_xor(s, 8, 64);
            s2 += __shfl_xor(s2, 1, 64); s2 += __shfl_xor(s2, 2, 64);
            s2 += __shfl_xor(s2, 4, 64); s2 += __shfl_xor(s2, 8, 64);
            if (cf == 0) {
                psum[gwid * OO + o]   = s;
                psumsq[gwid * OO + o] = s2;
            }
        }
    }
}

// ---- final stats: one block per channel ----
__global__ void finstats_kernel(const float* __restrict__ psum, const float* __restrict__ psumsq,
                                float* __restrict__ sums, float* __restrict__ sumsq) {
    const int o = blockIdx.x, l = threadIdx.x;   // 64 threads
    float s = 0.f, s2 = 0.f;
    for (int r = l; r < 896; r += 64) { s += psum[r * OO + o]; s2 += psumsq[r * OO + o]; }
    for (int off = 32; off > 0; off >>= 1) {
        s  += __shfl_down(s, off, 64);
        s2 += __shfl_down(s2, off, 64);
    }
    if (l == 0) { sums[o] = s; sumsq[o] = s2; }
}

// ---- BN + ReLU in place ----
__global__ void bn_kernel(float* __restrict__ out,
                          const float* __restrict__ sums, const float* __restrict__ sumsq,
                          const float* __restrict__ gamma, const float* __restrict__ beta) {
    const float invN = 1.0f / (float)(BB * HW);
    const int total4 = BB * OO * HW / 4;
    for (int i = blockIdx.x * blockDim.x + threadIdx.x; i < total4; i += gridDim.x * blockDim.x) {
        int o = (i / (HW/4)) % OO;
        float mean = sums[o] * invN;
        float var  = sumsq[o] * invN - mean*mean;
        float inv  = rsqrtf(var + EPSV);
        float g  = gamma[o] * inv;
        float bt = beta[o] - mean * g;
        float4 v = ((float4*)out)[i];
        v.x = fmaxf(v.x*g + bt, 0.f);
        v.y = fmaxf(v.y*g + bt, 0.f);
        v.z = fmaxf(v.z*g + bt, 0.f);
        v.w = fmaxf(v.w*g + bt, 0.f);
        ((float4*)out)[i] = v;
    }
}

extern "C" void kernel_launch(void* const* d_in, const int* in_sizes, int n_in,
                              void* d_out, int out_size, void* d_ws, size_t ws_size,
                              hipStream_t stream) {
    const float* x      = (const float*)d_in[0];
    const float* fc1_w  = (const float*)d_in[1];
    const float* fc1_b  = (const float*)d_in[2];
    const float* fc2_w  = (const float*)d_in[3];
    const float* fc2_b  = (const float*)d_in[4];
    const float* weight = (const float*)d_in[5];
    const float* bias   = (const float*)d_in[6];
    const float* gamma  = (const float*)d_in[7];
    const float* beta   = (const float*)d_in[8];
    float* out = (float*)d_out;

    const size_t XBF_ELEMS  = (size_t)BB * HW * CC;        // 12,845,056
    const size_t AGGW_ELEMS = (size_t)BB * 9 * OO * CC;    //  4,718,592
    ushort* xbf  = (ushort*)d_ws;
    ushort* aggw = xbf + XBF_ELEMS;
    float*  wsf  = (float*)(aggw + AGGW_ELEMS);
    float* pooledp = wsf;                    // 229376
    float* attn    = pooledp + 229376;       // 128
    float* agg_b   = attn + 128;             // 4096
    float* psum    = agg_b + 4096;           // 114688 (896*128)
    float* psumsq  = psum + 114688;          // 114688
    float* sums    = psumsq + 114688;        // 128
    float* sumsq   = sums + 128;             // 128
    ushort* zpage  = (ushort*)(sumsq + 128); // 32 shorts, zeroed by convert_pool

    convert_pool_kernel<<<dim3(HH, BB), 256, 0, stream>>>(x, xbf, pooledp, zpage);
    attn_kernel<<<BB, 128, 0, stream>>>(pooledp, fc1_w, fc1_b, fc2_w, fc2_b, attn);
    aggw_kernel<<<(int)((AGGW_ELEMS + 255)/256), 256, 0, stream>>>(attn, weight, bias, aggw, agg_b);
    conv_kernel<<<dim3(896), 256, 0, stream>>>(xbf, aggw, agg_b, zpage, out, psum, psumsq);
    finstats_kernel<<<OO, 64, 0, stream>>>(psum, psumsq, sums, sumsq);
    bn_kernel<<<2048, 256, 0, stream>>>(out, sums, sumsq, gamma, beta);
}

// Round 11
// 108.754 us; speedup vs baseline: 1.5179x; 1.0189x over previous
//
#include <hip/hip_runtime.h>
#include <hip/hip_bf16.h>

#define BB 32
#define CC 128
#define OO 128
#define HH 56
#define WW 56
#define KK 4
#define HW 3136
#define WPLANE 147456
#define EPSV 1e-5f

#define NP4 232                   // 4 input rows x 58 cols staged positions
#define BUF4 16384                // bytes per LDS buffer: 1024 units x 16 B (928 data + pad)

typedef __attribute__((ext_vector_type(8))) short short8v;
typedef __attribute__((ext_vector_type(4))) float f32x4;

static __device__ __forceinline__ void gload16(const void* g, void* l) {
    __builtin_amdgcn_global_load_lds((const __attribute__((address_space(1))) void*)g,
                                     (__attribute__((address_space(3))) void*)l, 16, 0, 0);
}

// ---- convert x -> bf16 channel-last [b][h][w][c], + per-(b,h,c) row sums ----
__global__ void convert_pool_kernel(const float* __restrict__ x,
                                    ushort* __restrict__ xbf,
                                    float* __restrict__ pooledp,
                                    ushort* __restrict__ zpage) {
    const int h = blockIdx.x, b = blockIdx.y;
    if (h == 0 && b == 0 && threadIdx.x < 32) zpage[threadIdx.x] = 0;
    __shared__ float4 xl4[1792];               // [c][w4] swizzled, 28672 B
    const float* xp = x + (size_t)(b * CC) * HW + h * WW;

    #pragma unroll
    for (int k = 0; k < 7; ++k) {
        int u = threadIdx.x + k * 256;
        int c = u / 14, w4 = u - c * 14;
        float4 v = *(const float4*)(xp + (size_t)c * HW + w4 * 4);
        xl4[u ^ ((c >> 3) & 7)] = v;
    }
    __syncthreads();

    const float* xf = (const float*)xl4;
    #pragma unroll
    for (int k = 0; k < 4; ++k) {
        int v = threadIdx.x + k * 256;
        if (v < 896) {
            int w = v >> 4, c8 = v & 15;
            int w4 = w >> 2, wo = w & 3;
            short8v res;
            #pragma unroll
            for (int j = 0; j < 8; ++j) {
                int c = c8 * 8 + j;
                int su = (c * 14 + w4) ^ (c8 & 7);
                __hip_bfloat16 hb = __float2bfloat16(xf[su * 4 + wo]);
                res[j] = *(short*)&hb;
            }
            *(short8v*)(xbf + ((size_t)((b * HH + h) * WW + w)) * CC + c8 * 8) = res;
        }
    }

    if (threadIdx.x < 128) {
        int c = threadIdx.x;
        float s = 0.f;
        #pragma unroll
        for (int w4 = 0; w4 < 14; ++w4) {
            float4 v = xl4[(c * 14 + w4) ^ ((c >> 3) & 7)];
            s += v.x + v.y + v.z + v.w;
        }
        pooledp[((size_t)(b * HH + h)) * CC + c] = s;
    }
}

// ---- attention: reduce pooled partials + tiny MLP + softmax. block per b ----
__global__ void attn_kernel(const float* __restrict__ pooledp,
                            const float* __restrict__ fc1_w, const float* __restrict__ fc1_b,
                            const float* __restrict__ fc2_w, const float* __restrict__ fc2_b,
                            float* __restrict__ attn) {
    const int b = blockIdx.x, c = threadIdx.x;      // 128 threads
    float s = 0.f;
    for (int h = 0; h < HH; ++h) s += pooledp[((size_t)(b * HH + h)) * CC + c];
    const float pc = s * (1.0f / HW);
    __shared__ float red[8];
    const int lane = c & 63, wid = c >> 6;
    #pragma unroll
    for (int k = 0; k < KK; ++k) {
        float v = pc * fc1_w[k * CC + c];
        for (int off = 32; off > 0; off >>= 1) v += __shfl_down(v, off, 64);
        if (lane == 0) red[k * 2 + wid] = v;
    }
    __syncthreads();
    if (c == 0) {
        float hk[KK], z[KK], m = -1e30f, den = 0.f;
        #pragma unroll
        for (int k = 0; k < KK; ++k)
            hk[k] = fmaxf(red[k * 2] + red[k * 2 + 1] + fc1_b[k], 0.f);
        #pragma unroll
        for (int k = 0; k < KK; ++k) {
            float t = fc2_b[k];
            #pragma unroll
            for (int j = 0; j < KK; ++j) t += hk[j] * fc2_w[k * KK + j];
            z[k] = t; m = fmaxf(m, t);
        }
        #pragma unroll
        for (int k = 0; k < KK; ++k) { z[k] = expf(z[k] - m); den += z[k]; }
        #pragma unroll
        for (int k = 0; k < KK; ++k) attn[b * KK + k] = z[k] / den;
    }
}

// ---- agg_w (bf16) in layout [b][j][ci][o][c32] + fused agg_b ----
__global__ void aggw_kernel(const float* __restrict__ attn, const float* __restrict__ weight,
                            const float* __restrict__ bias,
                            ushort* __restrict__ aggw, float* __restrict__ agg_b) {
    int idx = blockIdx.x * 256 + threadIdx.x;
    if (idx < BB * 9 * OO * CC) {
        int cc = idx & 31;
        int t1 = idx >> 5;
        int o  = t1 & 127;
        int t2 = t1 >> 7;
        int ci = t2 & 3;
        int t3 = t2 >> 2;
        int j  = t3 % 9;
        int b  = t3 / 9;
        int c  = ci * 32 + cc;
        size_t wi = ((size_t)(o * CC + c)) * 9 + j;
        float s = attn[b*KK + 0] * weight[wi]
                + attn[b*KK + 1] * weight[wi + (size_t)WPLANE]
                + attn[b*KK + 2] * weight[wi + (size_t)2*WPLANE]
                + attn[b*KK + 3] * weight[wi + (size_t)3*WPLANE];
        __hip_bfloat16 hb = __float2bfloat16(s);
        aggw[idx] = *(ushort*)&hb;
    }
    if (blockIdx.x < 16) {
        int i = blockIdx.x * 256 + threadIdx.x;   // 0..4095
        int b = i >> 7, o = i & 127;
        float s = 0.f;
        #pragma unroll
        for (int k = 0; k < KK; ++k) s += attn[b*KK + k] * bias[k*OO + o];
        agg_b[i] = s;
    }
}

// ---- implicit-GEMM conv: 896 blocks x 2 waves (2 o-halves), M_wave=64,
//      2-row tiles, gload_lds dbuf (src-permuted XOR swizzle), B tap-pipeline,
//      A rolling prefetch (coalesced layout), staging at tap 8 (no vmcnt drain),
//      XCD swizzle, fused stats ----
__launch_bounds__(128, 2)
__global__ void conv_kernel(const ushort* __restrict__ xbf, const ushort* __restrict__ aggw,
                            const float* __restrict__ agg_b, const ushort* __restrict__ zpage,
                            float* __restrict__ out,
                            float* __restrict__ psum, float* __restrict__ psumsq) {
    // XCD-aware swizzle: 896 blocks, each XCD gets 112 consecutive gwids = 4 samples.
    const int lid  = blockIdx.x;
    const int gwid = (lid & 7) * 112 + (lid >> 3);
    const int b = gwid / 28;
    const int t = gwid - b * 28;          // row-pair tile 0..27
    const int h0 = t * 2;
    __shared__ ushort xs[2 * BUF4 / 2];   // 32768 B

    const int tid  = threadIdx.x;
    const int lane = tid & 63;
    const int wg   = tid >> 6;            // o-half: o base = wg*64

    const int cf = lane & 15;
    const int kg = lane >> 4;

    // staging: 928 data units (1024 incl pad); 8 per thread. LDS slot un = tid+k*128
    // (byte un*16, wave-uniform base + lane*16) receives global unit
    // u = un ^ ((un>>3)&7) (involution within aligned 8-blocks). Halo/pad -> zpage.
    const ushort* gp[8]; int gstep[8];
    #pragma unroll
    for (int k = 0; k < 8; ++k) {
        int un = tid + k * 128;
        int u = un ^ ((un >> 3) & 7);
        int pos = u >> 2, quad = u & 3;
        int row = pos / 58, col = pos - row * 58;
        int gh = h0 - 1 + row, gw = col - 1;
        bool valid = (pos < NP4) && (gh >= 0) && (gh < HH) && (gw >= 0) && (gw < WW);
        gp[k] = valid ? (xbf + ((size_t)((b * HH + gh) * WW + gw)) * CC + quad * 8) : zpage;
        gstep[k] = valid ? 32 : 0;
    }

    // B-frag intra-buffer byte offsets (linear, pre-swizzle)
    int blin[7];
    #pragma unroll
    for (int nf = 0; nf < 7; ++nf) {
        int p = nf * 16 + cf;
        int r = p / 56, w = p - r * 56;
        blin[nf] = (((r + 1) * 58 + (w + 1)) << 6) + kg * 16;
    }

    f32x4 acc[4][7];
    #pragma unroll
    for (int mf = 0; mf < 4; ++mf)
        #pragma unroll
        for (int nf = 0; nf < 7; ++nf) acc[mf][nf] = (f32x4){0.f, 0.f, 0.f, 0.f};

    // A: aggw [b][j][ci][o][c32]; coalesced 1KB wave loads
    const ushort* Ab = aggw + ((size_t)b * 36) * 4096 + (size_t)(wg * 64 + cf) * 32 + kg * 8;
    #define ALOAD(mf_, j_, ci_) (*(const short8v*)(Ab + (size_t)((j_) * 4 + (ci_)) * 4096 + (mf_) * 512))

    short8v pa[4];
    #pragma unroll
    for (int mf = 0; mf < 4; ++mf) pa[mf] = ALOAD(mf, 0, 0);

    // prologue: stage chunk 0 into buf 0
    #pragma unroll
    for (int k = 0; k < 8; ++k) {
        gload16(gp[k], (char*)xs + (tid - lane + k * 128) * 16);
        gp[k] += gstep[k];
    }
    __syncthreads();

    int cur = 0;
    for (int ci = 0; ci < 4; ++ci) {
        const char* xbuf = (const char*)xs + cur * BUF4;

        // software-pipelined taps: read tap j+1's B while MFMA-ing tap j
        short8v bfc[7], bfn[7];
        #pragma unroll
        for (int nf = 0; nf < 7; ++nf) {
            int lin = blin[nf] + (-58 - 1) * 64;        // tap 0 (dh=-1,dw=-1)
            int swz = lin ^ ((lin >> 3) & 0x70);
            bfc[nf] = *(const short8v*)(xbuf + swz);
        }
        #pragma unroll
        for (int j = 0; j < 9; ++j) {
            if (j < 8) {
                const int toff = (((j+1)/3 - 1) * 58 + ((j+1)%3 - 1)) * 64;
                #pragma unroll
                for (int nf = 0; nf < 7; ++nf) {
                    int lin = blin[nf] + toff;
                    int swz = lin ^ ((lin >> 3) & 0x70);
                    bfn[nf] = *(const short8v*)(xbuf + swz);
                }
            }
            short8v ca[4];
            #pragma unroll
            for (int mf = 0; mf < 4; ++mf) ca[mf] = pa[mf];
            if (j < 8) {
                #pragma unroll
                for (int mf = 0; mf < 4; ++mf) pa[mf] = ALOAD(mf, j + 1, ci);
            } else if (ci < 3) {
                // last A-prefetch of the chunk, THEN issue staging: every
                // subsequent in-flight-A consume is OLDER than staging ->
                // counted vmcnt never drains the staging queue.
                #pragma unroll
                for (int mf = 0; mf < 4; ++mf) pa[mf] = ALOAD(mf, 0, ci + 1);
                char* base = (char*)xs + (cur ^ 1) * BUF4;
                #pragma unroll
                for (int k = 0; k < 8; ++k) {
                    gload16(gp[k], base + (tid - lane + k * 128) * 16);
                    gp[k] += gstep[k];
                }
            }
            #pragma unroll
            for (int nf = 0; nf < 7; ++nf) {
                #pragma unroll
                for (int mf = 0; mf < 4; ++mf)
                    acc[mf][nf] = __builtin_amdgcn_mfma_f32_16x16x32_bf16(ca[mf], bfc[nf], acc[mf][nf], 0, 0, 0);
            }
            if (j < 8) {
                #pragma unroll
                for (int nf = 0; nf < 7; ++nf) bfc[nf] = bfn[nf];
            }
        }
        if (ci < 3) __syncthreads();   // drains staging; 2-wave domain, 3.5 blocks/CU overlap
        cur ^= 1;
    }

    // ---- epilogue: bias add, store, fused stats partials ----
    #pragma unroll
    for (int mf = 0; mf < 4; ++mf) {
        #pragma unroll
        for (int i = 0; i < 4; ++i) {
            const int o = wg * 64 + mf * 16 + kg * 4 + i;
            const float ab = agg_b[b * OO + o];
            float* op = out + ((size_t)(b * OO + o)) * HW;
            float s = 0.f, s2 = 0.f;
            #pragma unroll
            for (int nf = 0; nf < 7; ++nf) {
                int p = nf * 16 + cf;
                int r = p / 56, w = p - r * 56;
                float v = acc[mf][nf][i] + ab;
                op[(h0 + r) * WW + w] = v;
                s += v; s2 += v * v;
            }
            s  += __shfl_xor(s, 1, 64);  s  += __shfl_xor(s, 2, 64);
            s  += __shfl_xor(s, 4, 64);  s  += __shfl_xor(s, 8, 64);
            s2 += __shfl_xor(s2, 1, 64); s2 += __shfl_xor(s2, 2, 64);
            s2 += __shfl_xor(s2, 4, 64); s2 += __shfl_xor(s2, 8, 64);
            if (cf == 0) {
                psum[gwid * OO + o]   = s;
                psumsq[gwid * OO + o] = s2;
            }
        }
    }
}

// ---- final stats: one block per channel ----
__global__ void finstats_kernel(const float* __restrict__ psum, const float* __restrict__ psumsq,
                                float* __restrict__ sums, float* __restrict__ sumsq) {
    const int o = blockIdx.x, l = threadIdx.x;   // 64 threads
    float s = 0.f, s2 = 0.f;
    for (int r = l; r < 896; r += 64) { s += psum[r * OO + o]; s2 += psumsq[r * OO + o]; }
    for (int off = 32; off > 0; off >>= 1) {
        s  += __shfl_down(s, off, 64);
        s2 += __shfl_down(s2, off, 64);
    }
    if (l == 0) { sums[o] = s; sumsq[o] = s2; }
}

// ---- BN + ReLU in place ----
__global__ void bn_kernel(float* __restrict__ out,
                          const float* __restrict__ sums, const float* __restrict__ sumsq,
                          const float* __restrict__ gamma, const float* __restrict__ beta) {
    const float invN = 1.0f / (float)(BB * HW);
    const int total4 = BB * OO * HW / 4;
    for (int i = blockIdx.x * blockDim.x + threadIdx.x; i < total4; i += gridDim.x * blockDim.x) {
        int o = (i / (HW/4)) % OO;
        float mean = sums[o] * invN;
        float var  = sumsq[o] * invN - mean*mean;
        float inv  = rsqrtf(var + EPSV);
        float g  = gamma[o] * inv;
        float bt = beta[o] - mean * g;
        float4 v = ((float4*)out)[i];
        v.x = fmaxf(v.x*g + bt, 0.f);
        v.y = fmaxf(v.y*g + bt, 0.f);
        v.z = fmaxf(v.z*g + bt, 0.f);
        v.w = fmaxf(v.w*g + bt, 0.f);
        ((float4*)out)[i] = v;
    }
}

extern "C" void kernel_launch(void* const* d_in, const int* in_sizes, int n_in,
                              void* d_out, int out_size, void* d_ws, size_t ws_size,
                              hipStream_t stream) {
    const float* x      = (const float*)d_in[0];
    const float* fc1_w  = (const float*)d_in[1];
    const float* fc1_b  = (const float*)d_in[2];
    const float* fc2_w  = (const float*)d_in[3];
    const float* fc2_b  = (const float*)d_in[4];
    const float* weight = (const float*)d_in[5];
    const float* bias   = (const float*)d_in[6];
    const float* gamma  = (const float*)d_in[7];
    const float* beta   = (const float*)d_in[8];
    float* out = (float*)d_out;

    const size_t XBF_ELEMS  = (size_t)BB * HW * CC;        // 12,845,056
    const size_t AGGW_ELEMS = (size_t)BB * 9 * OO * CC;    //  4,718,592
    ushort* xbf  = (ushort*)d_ws;
    ushort* aggw = xbf + XBF_ELEMS;
    float*  wsf  = (float*)(aggw + AGGW_ELEMS);
    float* pooledp = wsf;                    // 229376
    float* attn    = pooledp + 229376;       // 128
    float* agg_b   = attn + 128;             // 4096
    float* psum    = agg_b + 4096;           // 114688 (896*128)
    float* psumsq  = psum + 114688;          // 114688
    float* sums    = psumsq + 114688;        // 128
    float* sumsq   = sums + 128;             // 128
    ushort* zpage  = (ushort*)(sumsq + 128); // 32 shorts, zeroed by convert_pool

    convert_pool_kernel<<<dim3(HH, BB), 256, 0, stream>>>(x, xbf, pooledp, zpage);
    attn_kernel<<<BB, 128, 0, stream>>>(pooledp, fc1_w, fc1_b, fc2_w, fc2_b, attn);
    aggw_kernel<<<(int)((AGGW_ELEMS + 255)/256), 256, 0, stream>>>(attn, weight, bias, aggw, agg_b);
    conv_kernel<<<dim3(896), 128, 0, stream>>>(xbf, aggw, agg_b, zpage, out, psum, psumsq);
    finstats_kernel<<<OO, 64, 0, stream>>>(psum, psumsq, sums, sumsq);
    bn_kernel<<<2048, 256, 0, stream>>>(out, sums, sumsq, gamma, beta);
}